// Round 12
// baseline (7101.733 us; speedup 1.0000x reference)
//
#include <hip/hip_runtime.h>

namespace {

constexpr int NB    = 256;
constexpr int NT    = 1024;
constexpr int NSTEP = NT - 1;
constexpr int D = 4, H = 64, W = 128;

constexpr float cAT[6][5] = {
    {0.f, 0.f, 0.f, 0.f, 0.f},
    {0.161f, 0.f, 0.f, 0.f, 0.f},
    {-0.008480655492356989f, 0.335480655492357f, 0.f, 0.f, 0.f},
    {2.8971530571054935f, -6.359448489975075f, 4.3622954328695815f, 0.f, 0.f},
    {5.325864828439257f, -11.748883564062828f, 7.4955393428898365f, -0.09249506636175525f, 0.f},
    {5.86145544294642f, -12.92096931784711f, 8.159367898576159f, -0.071584973281401f, -0.028269050394068383f}};
constexpr float cFR[6] = {0.0f, 0.161f, 0.327f, 0.9f, 0.9800255409045097f, 1.0f};
constexpr float cBW[6] = {0.09646076681806523f, 0.01f, 0.4798896504144996f,
                          1.379008574103742f, -3.290069515436081f, 2.324710524099774f};

__device__ __forceinline__ float softplus_f(float x) {
    float e = __expf(-fabsf(x));
    return fmaxf(x, 0.0f) + __logf(1.0f + e);
}
__device__ __forceinline__ float tanh_f(float x) {
    float e = __expf(2.0f * x);
    return 1.0f - __fdividef(2.0f, 1.0f + e);
}

// DPP lane exchanges. 0xB1 (xor1) / 0x4E (xor2): quad_perm involutions.
// 0x141 row_half_mirror: i<->7-i within 8 (involution, validated R6/R11).
// 0x128 row_ror:8: within a 16-lane row, (i+-8)%16 == i^8 -> exact xor8 either
//   direction (validated numerically in R7's passing run).
// 0x124 row_ror:4: applied ONLY after an xor8 fold; then (i+-4)%16 differs from
//   i^4 by a multiple of 8 where values are already equal -> acts as xor4,
//   direction-proof.
template <int CTRL>
__device__ __forceinline__ float dppmv(float x) {
    return __int_as_float(__builtin_amdgcn_mov_dpp(__float_as_int(x), CTRL, 0xF, 0xF, true));
}

// Padded LDS index maps (R6/R11-validated):
__device__ __forceinline__ int pY(int i)  { return (i >> 4) * 20 + (i & 15); }  // s_ys : 4x20
__device__ __forceinline__ int p1i(int i) { return (i >> 5) * 36 + (i & 31); }  // s_h1 : 4x36
__device__ __forceinline__ int p2i(int i) { return (i >> 6) * 72 + (i & 63); }  // s_h2 : 2x72

__global__ __launch_bounds__(1024, 4)
void cde_kernel(const float* __restrict__ ts,
                const float* __restrict__ coef_d,
                const float* __restrict__ coef_c,
                const float* __restrict__ coef_b,
                const float* __restrict__ coef_a,
                const float* __restrict__ W0, const float* __restrict__ b0,
                const float* __restrict__ W1, const float* __restrict__ b1,
                const float* __restrict__ W2, const float* __restrict__ b2,
                const float* __restrict__ F0, const float* __restrict__ g0,
                const float* __restrict__ F1, const float* __restrict__ g1,
                const float* __restrict__ F2, const float* __restrict__ g2,
                const float* __restrict__ Lm, const float* __restrict__ lb,
                float* __restrict__ out)
{
    const int b    = blockIdx.x;
    const int tid  = threadIdx.x;

    const int par  = tid & 1;     // which of the pair's 2 outputs this lane finalizes
    const int qAB  = tid & 15;    // A/B slice id within 16-lane pair-group
    const int pg   = tid >> 4;    // A/B pair id (64) == h owner (RK state)
    const int qc   = tid & 7;     // C slice id within 8-lane pair-group
    const int cg   = tid >> 3;    // C pair id (128)
    const int dsel = ((tid >> 3) & 1) * 2 + par;   // d of this lane's C output

    __shared__ __align__(16) float s_ys[80];
    __shared__ __align__(16) float s_h1[144];
    __shared__ __align__(16) float s_h2[136];

    // -------- persistent weights: 56 floats/thread (fits 128-VGPR budget) --------
    float wA0[4], wA1[4];      // F0[2pg+{0,1}][4qAB .. +3]
    float wB0[8], wB1[8];      // F1[2pg+{0,1}][8qAB .. +7]
    float wC0[16], wC1[16];    // F2[2cg+{0,1}][16qc .. +15]
    {
        float4 v0 = *reinterpret_cast<const float4*>(F0 + (2*pg)     * H + 4*qAB);
        float4 v1 = *reinterpret_cast<const float4*>(F0 + (2*pg + 1) * H + 4*qAB);
        wA0[0]=v0.x; wA0[1]=v0.y; wA0[2]=v0.z; wA0[3]=v0.w;
        wA1[0]=v1.x; wA1[1]=v1.y; wA1[2]=v1.z; wA1[3]=v1.w;
    }
    #pragma unroll
    for (int i = 0; i < 8; i += 4) {
        float4 v0 = *reinterpret_cast<const float4*>(F1 + (2*pg)     * W + 8*qAB + i);
        float4 v1 = *reinterpret_cast<const float4*>(F1 + (2*pg + 1) * W + 8*qAB + i);
        wB0[i+0]=v0.x; wB0[i+1]=v0.y; wB0[i+2]=v0.z; wB0[i+3]=v0.w;
        wB1[i+0]=v1.x; wB1[i+1]=v1.y; wB1[i+2]=v1.z; wB1[i+3]=v1.w;
    }
    #pragma unroll
    for (int i = 0; i < 16; i += 4) {
        float4 v0 = *reinterpret_cast<const float4*>(F2 + (2*cg)     * W + 16*qc + i);
        float4 v1 = *reinterpret_cast<const float4*>(F2 + (2*cg + 1) * W + 16*qc + i);
        wC0[i+0]=v0.x; wC0[i+1]=v0.y; wC0[i+2]=v0.z; wC0[i+3]=v0.w;
        wC1[i+0]=v1.x; wC1[i+1]=v1.y; wC1[i+2]=v1.z; wC1[i+3]=v1.w;
    }
    const float g0s = g0[2*pg + par];
    const float g1s = g1[2*pg + par];
    const float g2s = g2[2*cg + par];
    const float L0r = Lm[0*H + (tid & 63)];
    const float L1r = Lm[1*H + (tid & 63)];
    const float L2r = Lm[2*H + (tid & 63)];
    const float lb0 = lb[0], lb1 = lb[1], lb2 = lb[2];

    // LDS pointers (16B-aligned bases; consistent with pY/p1i/p2i layouts).
    const float* pA = s_ys + (qAB >> 2) * 20 + (qAB & 3) * 4;   // = pY(4*qAB)
    const float* pB = s_h1 + (qAB >> 2) * 36 + (qAB & 3) * 8;   // = p1i(8*qAB)
    const float* pC = s_h2 + (qc  >> 2) * 72 + (qc  & 3) * 16;  // = p2i(16*qc)
    float* pw1 = s_h1 + p1i(2*pg + par);   // valid writer when qAB < 2
    float* pw2 = s_h2 + p2i(2*pg + par);
    float* pwy = s_ys + pY(pg);

    // 16-lane parity reduce-scatter: returns full dot for output (2*group+par).
    auto red16 = [&](float p0, float p1) -> float {
        float s = par ? p1 : p0;
        float o = par ? p0 : p1;
        s += dppmv<0xB1>(o);    // fold parity-partner slice (parity-preserving after)
        s += dppmv<0x4E>(s);    // xor2
        s += dppmv<0x128>(s);   // xor8
        s += dppmv<0x124>(s);   // xor4 (valid after xor8 fold)
        return s;
    };

    // ---------------- initial y0 = MLP(x0) (R11-validated path) ----------------
    if (tid < W) {
        const float4 x0 = *reinterpret_cast<const float4*>(coef_a + (size_t)b * NSTEP * D);
        const float4 w  = *reinterpret_cast<const float4*>(W0 + tid * D);
        s_h1[p1i(tid)] = softplus_f(w.x*x0.x + w.y*x0.y + w.z*x0.z + w.w*x0.w + b0[tid]);
    }
    __syncthreads();
    if (tid < W) {
        float a = b1[tid];
        #pragma unroll
        for (int blk = 0; blk < 4; ++blk)
            #pragma unroll
            for (int i = 0; i < 8; ++i) {
                float4 wv = *reinterpret_cast<const float4*>(W1 + tid * W + blk * 32 + 4 * i);
                float4 hv = *reinterpret_cast<const float4*>(s_h1 + blk * 36 + 4 * i);
                a += wv.x*hv.x + wv.y*hv.y + wv.z*hv.z + wv.w*hv.w;
            }
        s_h2[p2i(tid)] = softplus_f(a);
    }
    __syncthreads();
    if (tid < H) {
        float a = b2[tid];
        #pragma unroll
        for (int blk = 0; blk < 2; ++blk)
            #pragma unroll
            for (int i = 0; i < 16; ++i) {
                float4 wv = *reinterpret_cast<const float4*>(W2 + tid * W + blk * 64 + 4 * i);
                float4 hv = *reinterpret_cast<const float4*>(s_h2 + blk * 72 + 4 * i);
                a += wv.x*hv.x + wv.y*hv.y + wv.z*hv.z + wv.w*hv.w;
            }
        s_ys[pY(tid)] = a;
    }
    __syncthreads();

    float y = s_ys[pY(pg)];

    auto project = [&](int tslot) {
        if (tid < 64) {
            float yv = s_ys[pY(tid)];
            float p0 = yv * L0r, p1 = yv * L1r, p2 = yv * L2r;
            #pragma unroll
            for (int off = 32; off >= 1; off >>= 1) {
                p0 += __shfl_xor(p0, off);
                p1 += __shfl_xor(p1, off);
                p2 += __shfl_xor(p2, off);
            }
            if (tid == 0) {
                float* dst = out + ((size_t)b * NT + tslot) * 3;
                dst[0] = p0 + lb0; dst[1] = p1 + lb1; dst[2] = p2 + lb2;
            }
        }
    };
    project(0);

    const float* cb_pl = coef_b + (size_t)b * NSTEP * D + dsel;
    const float* cc_pl = coef_c + (size_t)b * NSTEP * D + dsel;
    const float* cd_pl = coef_d + (size_t)b * NSTEP * D + dsel;

    // ---------------- main scan: 1023 steps x 6 stages, 3 barriers/stage ----------------
    for (int t = 0; t < NSTEP; ++t) {
        const float cbd = cb_pl[(size_t)t * D];
        const float ccd = cc_pl[(size_t)t * D];
        const float cdd = cd_pl[(size_t)t * D];
        const float dtv = ts[t + 1] - ts[t];

        float k[6];

        #pragma unroll
        for (int s = 0; s < 6; ++s) {
            // ---- Phase A: L1 (64 -> 128), 16-lane pair-group, 4-slice ----
            {
                float4 hv = *reinterpret_cast<const float4*>(pA);
                float p0 = wA0[0]*hv.x + wA0[1]*hv.y + wA0[2]*hv.z + wA0[3]*hv.w;
                float p1 = wA1[0]*hv.x + wA1[1]*hv.y + wA1[2]*hv.z + wA1[3]*hv.w;
                float c = red16(p0, p1);
                if (qAB < 2) *pw1 = softplus_f(c + g0s);
            }
            __syncthreads();

            // ---- Phase B: L2 (128 -> 128), 16-lane pair-group, 8-slice ----
            {
                float4 u0 = *reinterpret_cast<const float4*>(pB + 0);
                float4 u1 = *reinterpret_cast<const float4*>(pB + 4);
                float p0 = wB0[0]*u0.x + wB0[1]*u0.y + wB0[2]*u0.z + wB0[3]*u0.w
                         + wB0[4]*u1.x + wB0[5]*u1.y + wB0[6]*u1.z + wB0[7]*u1.w;
                float p1 = wB1[0]*u0.x + wB1[1]*u0.y + wB1[2]*u0.z + wB1[3]*u0.w
                         + wB1[4]*u1.x + wB1[5]*u1.y + wB1[6]*u1.z + wB1[7]*u1.w;
                float c = red16(p0, p1);
                if (qAB < 2) *pw2 = softplus_f(c + g1s);
            }
            __syncthreads();

            // ---- Phase C: L3 (128 -> 256), 8-lane pair-group + einsum + RK ----
            {
                float p0 = 0.f, p1 = 0.f;
                #pragma unroll
                for (int m = 0; m < 4; ++m) {
                    float4 u = *reinterpret_cast<const float4*>(pC + 4*m);
                    p0 += wC0[4*m+0]*u.x + wC0[4*m+1]*u.y + wC0[4*m+2]*u.z + wC0[4*m+3]*u.w;
                    p1 += wC1[4*m+0]*u.x + wC1[4*m+1]*u.y + wC1[4*m+2]*u.z + wC1[4*m+3]*u.w;
                }
                // 8-lane all-reduce of both dots (R11-validated pattern).
                p0 += dppmv<0xB1>(p0); p1 += dppmv<0xB1>(p1);
                p0 += dppmv<0x4E>(p0); p1 += dppmv<0x4E>(p1);
                p0 += dppmv<0x141>(p0); p1 += dppmv<0x141>(p1);
                const float ft = tanh_f((par ? p1 : p0) + g2s);

                const float frac = cFR[s] * dtv;
                const float dxd  = fmaf(frac, fmaf(3.0f * frac, cdd, 2.0f * ccd), cbd);
                // 16-lane h-group: lane j holds f_d with d=(j>>3)*2+(j&1), each d
                // appears 4x across the group -> sum * 0.25 = k[h].
                float pk = ft * dxd * 0.25f;
                pk += dppmv<0xB1>(pk);
                pk += dppmv<0x4E>(pk);
                pk += dppmv<0x128>(pk);
                pk += dppmv<0x124>(pk);     // xor4 (valid after xor8 fold)
                k[s] = pk;

                float ysn;
                if (s < 5) {
                    float acc = 0.f;
                    #pragma unroll
                    for (int i = 0; i <= s; ++i) acc = fmaf(cAT[s+1][i], k[i], acc);
                    ysn = fmaf(dtv, acc, y);
                } else {
                    float acc = 0.f;
                    #pragma unroll
                    for (int i = 0; i < 6; ++i) acc = fmaf(cBW[i], k[i], acc);
                    ysn = fmaf(dtv, acc, y);
                }
                if ((tid & 15) == 0) *pwy = ysn;
            }
            __syncthreads();
        }

        y = *pwy;          // refresh from the writer lane's stored value
        project(t + 1);    // wave0 projects while other waves start next phase A
    }
}

} // namespace

extern "C" void kernel_launch(void* const* d_in, const int* in_sizes, int n_in,
                              void* d_out, int out_size, void* d_ws, size_t ws_size,
                              hipStream_t stream) {
    const float* ts     = (const float*)d_in[0];
    const float* coef_d = (const float*)d_in[1];
    const float* coef_c = (const float*)d_in[2];
    const float* coef_b = (const float*)d_in[3];
    const float* coef_a = (const float*)d_in[4];
    const float* W0 = (const float*)d_in[5];
    const float* b0 = (const float*)d_in[6];
    const float* W1 = (const float*)d_in[7];
    const float* b1 = (const float*)d_in[8];
    const float* W2 = (const float*)d_in[9];
    const float* b2 = (const float*)d_in[10];
    const float* F0 = (const float*)d_in[11];
    const float* g0 = (const float*)d_in[12];
    const float* F1 = (const float*)d_in[13];
    const float* g1 = (const float*)d_in[14];
    const float* F2 = (const float*)d_in[15];
    const float* g2 = (const float*)d_in[16];
    const float* Lm = (const float*)d_in[17];
    const float* lb = (const float*)d_in[18];
    float* out = (float*)d_out;

    hipLaunchKernelGGL(cde_kernel, dim3(NB), dim3(1024), 0, stream,
                       ts, coef_d, coef_c, coef_b, coef_a,
                       W0, b0, W1, b1, W2, b2,
                       F0, g0, F1, g1, F2, g2, Lm, lb, out);
}